// Round 4
// baseline (624.146 us; speedup 1.0000x reference)
//
#include <hip/hip_runtime.h>

#define SS 192
#define DD 128
#define SAN 16384                     // stage-A row length (128*128)
#define PITCH 136                     // LDS row pitch in bf16 elements (272B, 16B-aligned)

typedef short bf8v __attribute__((ext_vector_type(8)));   // 8 x bf16
typedef float f4v  __attribute__((ext_vector_type(4)));

__device__ __forceinline__ unsigned short f2bf(float f) {
    union { float f; unsigned u; } v; v.f = f;
    unsigned r = v.u + 0x7fffu + ((v.u >> 16) & 1u);
    return (unsigned short)(r >> 16);
}

__device__ __forceinline__ unsigned pack2(float a, float b) {
    return (unsigned)f2bf(a) | ((unsigned)f2bf(b) << 16);
}

__device__ __forceinline__ f4v mfma16(bf8v a, bf8v b, f4v c) {
    return __builtin_amdgcn_mfma_f32_16x16x32_bf16(a, b, c, 0, 0, 0);
}

// ---------------- K0a: MLP projections, K-chunked partials (f32) ---------------
__global__ __launch_bounds__(256) void proj_part(
    const float* __restrict__ x,
    const float* __restrict__ Wp, const float* __restrict__ Wh,
    const float* __restrict__ Wt, float* __restrict__ part)
{
    __shared__ float xs[8 * 256];
    int r0 = blockIdx.x * 8;
    int w  = blockIdx.y;
    int kc = blockIdx.z;
    const float* W = (w == 0) ? Wp : (w == 1) ? Wh : Wt;
    int tid = threadIdx.x;
    for (int u = tid; u < 512; u += 256) {
        int row = u >> 6, k4 = u & 63;
        *(float4*)(&xs[row * 256 + k4 * 4]) =
            *(const float4*)(&x[(size_t)(r0 + row) * 1024 + kc * 256 + k4 * 4]);
    }
    __syncthreads();
    int col = tid & 127, rg = tid >> 7;
    float acc[4] = {0.f, 0.f, 0.f, 0.f};
    const float* Wk = W + (size_t)(kc * 256) * 128 + col;
    #pragma unroll 8
    for (int k = 0; k < 256; ++k) {
        float wv = Wk[(size_t)k * 128];
        #pragma unroll
        for (int r = 0; r < 4; ++r) acc[r] += xs[(rg * 4 + r) * 256 + k] * wv;
    }
    float* pp = part + (((size_t)w * 4 + kc) * 384) * 128;
    #pragma unroll
    for (int r = 0; r < 4; ++r)
        pp[(size_t)(r0 + rg * 4 + r) * 128 + col] = acc[r];
}

// ---------------- K0b: finalize: sum 4 partials + bias + leaky + bf16 ----------
__global__ __launch_bounds__(256) void proj_fin(
    const float* __restrict__ part,
    const float* __restrict__ bp, const float* __restrict__ bh,
    const float* __restrict__ bt,
    unsigned short* __restrict__ Pb, unsigned short* __restrict__ SHb,
    unsigned short* __restrict__ STb)
{
    int r0 = blockIdx.x * 8;
    int w  = blockIdx.y;
    const float* bias = (w == 0) ? bp : (w == 1) ? bh : bt;
    unsigned short* O = (w == 0) ? Pb : (w == 1) ? SHb : STb;
    int tid = threadIdx.x;
    int col = tid & 127, rg = tid >> 7;
    const float* pw = part + ((size_t)w * 4) * 384 * 128;
    float bb = bias[col];
    #pragma unroll
    for (int r = 0; r < 4; ++r) {
        int row = r0 + rg * 4 + r;
        float s = pw[(size_t)row * 128 + col]
                + pw[(size_t)(384 + row) * 128 + col]
                + pw[(size_t)(2 * 384 + row) * 128 + col]
                + pw[(size_t)(3 * 384 + row) * 128 + col];
        s += bb;
        s = s > 0.f ? s : 0.1f * s;
        O[(size_t)row * 128 + col] = f2bf(s);
    }
}

// ---------------- K1: merged weight prep ---------------------------------------
// sel<4 (rev):  in[i][k][j] -> Wprep[j][i][k]   (blockIdx.y = i)
// sel>=4 (cop): in[i][k][j] -> Wprep[j][k][i]   (blockIdx.y = k)
__global__ __launch_bounds__(256) void prep_all(
    const float* __restrict__ w0, const float* __restrict__ w1,
    const float* __restrict__ w2, const float* __restrict__ w3,
    const float* __restrict__ w4, const float* __restrict__ w5,
    unsigned short* __restrict__ Wprep)
{
    __shared__ float tile[32][33];
    int sel = blockIdx.z;
    const float* in = (sel == 0) ? w0 : (sel == 1) ? w1 : (sel == 2) ? w2
                    : (sel == 3) ? w3 : (sel == 4) ? w4 : w5;
    unsigned short* out = Wprep + (size_t)sel * 2097152;
    int a  = blockIdx.y;                                   // i (rev) or k (cop)
    int ct = (blockIdx.x >> 2) * 32, jt = (blockIdx.x & 3) * 32;  // k (rev) or i (cop)
    int tx = threadIdx.x & 31, ty = threadIdx.x >> 5;
    if (sel < 4) {
        #pragma unroll
        for (int r = 0; r < 4; ++r)
            tile[ty + r * 8][tx] = in[((size_t)a * 128 + ct + ty + r * 8) * 128 + jt + tx];
    } else {
        #pragma unroll
        for (int r = 0; r < 4; ++r)
            tile[ty + r * 8][tx] = in[((size_t)(ct + ty + r * 8) * 128 + a) * 128 + jt + tx];
    }
    __syncthreads();
    #pragma unroll
    for (int r = 0; r < 4; ++r) {
        int j = jt + ty + r * 8;
        out[((size_t)j * 128 + a) * 128 + ct + tx] = f2bf(tile[tx][ty + r * 8]);
    }
}

// ---------------- K2: stage A GEMMs: SA[slot] (384x16384) = P(384x128)@Wprep^T --
__global__ __launch_bounds__(256) void stageA(
    const unsigned short* __restrict__ Pb,
    const unsigned short* __restrict__ Wprep, unsigned short* __restrict__ SAout)
{
    __shared__ unsigned short BL[64 * PITCH];
    int slot = blockIdx.y;
    int n0 = blockIdx.x * 64;
    const unsigned short* Wn = Wprep + (size_t)slot * 2097152 + (size_t)n0 * 128;
    unsigned short* Oo = SAout + (size_t)slot * ((size_t)384 * SAN);
    int tid = threadIdx.x;
    for (int u = tid; u < 1024; u += 256) {
        int e = u * 8; int r = e >> 7; int c = e & 127;
        *(uint4*)(&BL[r * PITCH + c]) = *(const uint4*)(&Wn[e]);
    }
    __syncthreads();
    int wave = tid >> 6, lane = tid & 63, m = lane & 15, quad = lane >> 4;
    const unsigned short* br = &BL[(wave * 16 + m) * PITCH + quad * 8];
    bf8v b0 = *(const bf8v*)(br);
    bf8v b1 = *(const bf8v*)(br + 32);
    bf8v b2 = *(const bf8v*)(br + 64);
    bf8v b3 = *(const bf8v*)(br + 96);
    for (int mt = 0; mt < 24; mt += 2) {
        const unsigned short* ar0 = Pb + (size_t)(mt * 16 + m) * 128 + quad * 8;
        const unsigned short* ar1 = ar0 + 16 * 128;
        f4v acc0 = {0.f, 0.f, 0.f, 0.f}, acc1 = {0.f, 0.f, 0.f, 0.f};
        acc0 = mfma16(*(const bf8v*)(ar0),      b0, acc0);
        acc1 = mfma16(*(const bf8v*)(ar1),      b0, acc1);
        acc0 = mfma16(*(const bf8v*)(ar0 + 32), b1, acc0);
        acc1 = mfma16(*(const bf8v*)(ar1 + 32), b1, acc1);
        acc0 = mfma16(*(const bf8v*)(ar0 + 64), b2, acc0);
        acc1 = mfma16(*(const bf8v*)(ar1 + 64), b2, acc1);
        acc0 = mfma16(*(const bf8v*)(ar0 + 96), b3, acc0);
        acc1 = mfma16(*(const bf8v*)(ar1 + 96), b3, acc1);
        unsigned short* orow0 = Oo + (size_t)(mt * 16) * SAN + n0 + wave * 16;
        unsigned short* orow1 = orow0 + (size_t)16 * SAN;
        #pragma unroll
        for (int r = 0; r < 4; ++r) {
            orow0[(size_t)(quad * 4 + r) * SAN + m] = f2bf(acc0[r]);
            orow1[(size_t)(quad * 4 + r) * SAN + m] = f2bf(acc1[r]);
        }
    }
}

// ---------------- K3: merged stage B (8-wave blocks): t=0..3 sym, 4 ph, 5 pt ---
// phase 1 computed transposed (A = wz^T rows from LDS, B = X/Z frag) so the
// output fragment holds 4 consecutive j per lane -> packed ds_write_b64.
// 2 blocks/CU (69.6 KB LDS) x 8 waves = 4 waves/SIMD.
__global__ __launch_bounds__(512, 4) void stageB_all(
    const unsigned short* __restrict__ Pb, const unsigned short* __restrict__ SHb,
    const unsigned short* __restrict__ STb, const unsigned short* __restrict__ SA,
    float* __restrict__ out)
{
    __shared__ unsigned short WZT[128 * PITCH];
    __shared__ unsigned short Tst[128 * PITCH];
    const size_t OUTN = (size_t)2 * SS * SS * SS;

    int t  = blockIdx.y;
    int bz = blockIdx.x;
    int b  = bz / SS;
    int tid = threadIdx.x;

    // stage SA slice (32 KB) for this (t, bz); layout [j][k]
    const unsigned short* src = SA + ((size_t)t * 384 + bz) * SAN;
    for (int u = tid; u < 2048; u += 512) {
        int e = u * 8; int j = e >> 7; int i = e & 127;
        *(uint4*)(&WZT[j * PITCH + i]) = *(const uint4*)(&src[e]);
    }
    __syncthreads();

    int wave = tid >> 6, lane = tid & 63, m = lane & 15, quad = lane >> 4;
    unsigned short* TrowB = &Tst[(size_t)wave * 16 * PITCH];
    const unsigned short* Ta = &Tst[((size_t)wave * 16 + m) * PITCH + quad * 8];

    // phase 1: T^T tiles = mfma(wz^T j-rows, frag) -> Tst[x|z][j], packed writes.
    auto phase1 = [&](const unsigned short* fr, bf8v* tout) {
        bf8v a0 = *(const bf8v*)(fr);
        bf8v a1 = *(const bf8v*)(fr + 32);
        bf8v a2 = *(const bf8v*)(fr + 64);
        bf8v a3 = *(const bf8v*)(fr + 96);
        #pragma unroll
        for (int jt = 0; jt < 8; jt += 2) {
            const unsigned short* w0 = &WZT[(jt * 16 + m) * PITCH + quad * 8];
            const unsigned short* w1 = w0 + 16 * PITCH;
            f4v acc0 = {0.f,0.f,0.f,0.f}, acc1 = {0.f,0.f,0.f,0.f};
            acc0 = mfma16(*(const bf8v*)(w0),      a0, acc0);
            acc1 = mfma16(*(const bf8v*)(w1),      a0, acc1);
            acc0 = mfma16(*(const bf8v*)(w0 + 32), a1, acc0);
            acc1 = mfma16(*(const bf8v*)(w1 + 32), a1, acc1);
            acc0 = mfma16(*(const bf8v*)(w0 + 64), a2, acc0);
            acc1 = mfma16(*(const bf8v*)(w1 + 64), a2, acc1);
            acc0 = mfma16(*(const bf8v*)(w0 + 96), a3, acc0);
            acc1 = mfma16(*(const bf8v*)(w1 + 96), a3, acc1);
            uint2 v0, v1;
            v0.x = pack2(acc0[0], acc0[1]); v0.y = pack2(acc0[2], acc0[3]);
            v1.x = pack2(acc1[0], acc1[1]); v1.y = pack2(acc1[2], acc1[3]);
            *(uint2*)(&TrowB[m * PITCH + jt * 16 + quad * 4])       = v0;
            *(uint2*)(&TrowB[m * PITCH + (jt + 1) * 16 + quad * 4]) = v1;
        }
        tout[0] = *(const bf8v*)(Ta);
        tout[1] = *(const bf8v*)(Ta + 32);
        tout[2] = *(const bf8v*)(Ta + 64);
        tout[3] = *(const bf8v*)(Ta + 96);
    };

    if (t < 4) {
        // -------- symmetric triaffine path (block = (b, z)) --------
        const unsigned short* X = (t == 3) ? STb : SHb;
        const unsigned short* Y = (t == 2) ? SHb : STb;
        float* O = out + (size_t)t * OUTN + (size_t)bz * SS * SS;
        const unsigned short* Xb = X + (size_t)b * SS * DD;
        const unsigned short* Yb = Y + (size_t)b * SS * DD;

        // m-tile ownership: waves 0-3 -> {w}; waves 4-7 -> {w, 15-w}
        int mt0 = wave;
        int mt1 = 15 - wave;
        bool two = (wave >= 4);

        bf8v ta0[4], ta1[4];
        phase1(Xb + (size_t)(mt0 * 16 + m) * DD + quad * 8, ta0);
        if (two) phase1(Xb + (size_t)(mt1 * 16 + m) * DD + quad * 8, ta1);

        for (int yt = mt0; yt < 12; ++yt) {
            const unsigned short* yr = Yb + (size_t)(yt * 16 + m) * DD + quad * 8;
            bf8v yv0 = *(const bf8v*)(yr);
            bf8v yv1 = *(const bf8v*)(yr + 32);
            bf8v yv2 = *(const bf8v*)(yr + 64);
            bf8v yv3 = *(const bf8v*)(yr + 96);
            bool c1 = two && (yt >= mt1);
            f4v acc0 = {0.f,0.f,0.f,0.f}, acc1 = {0.f,0.f,0.f,0.f};
            acc0 = mfma16(ta0[0], yv0, acc0);
            acc0 = mfma16(ta0[1], yv1, acc0);
            acc0 = mfma16(ta0[2], yv2, acc0);
            acc0 = mfma16(ta0[3], yv3, acc0);
            if (c1) {
                acc1 = mfma16(ta1[0], yv0, acc1);
                acc1 = mfma16(ta1[1], yv1, acc1);
                acc1 = mfma16(ta1[2], yv2, acc1);
                acc1 = mfma16(ta1[3], yv3, acc1);
            }
            // store tile (mt0, yt)
            {
                int xs_ = mt0 * 16, ys_ = yt * 16, cc = m;
                if (yt == mt0) {
                    #pragma unroll
                    for (int r = 0; r < 4; ++r) {
                        int rr = quad * 4 + r;
                        if (rr <= cc) O[(size_t)(xs_ + rr) * SS + xs_ + cc] = acc0[r];
                        if (cc > rr)  O[(size_t)(xs_ + cc) * SS + xs_ + rr] = acc0[r];
                    }
                } else {
                    #pragma unroll
                    for (int r = 0; r < 4; ++r)
                        O[(size_t)(xs_ + quad * 4 + r) * SS + ys_ + cc] = acc0[r];
                    *(f4v*)(&O[(size_t)(ys_ + cc) * SS + xs_ + quad * 4]) = acc0;
                }
            }
            if (c1) {
                int xs_ = mt1 * 16, ys_ = yt * 16, cc = m;
                if (yt == mt1) {
                    #pragma unroll
                    for (int r = 0; r < 4; ++r) {
                        int rr = quad * 4 + r;
                        if (rr <= cc) O[(size_t)(xs_ + rr) * SS + xs_ + cc] = acc1[r];
                        if (cc > rr)  O[(size_t)(xs_ + cc) * SS + xs_ + rr] = acc1[r];
                    }
                } else {
                    #pragma unroll
                    for (int r = 0; r < 4; ++r)
                        O[(size_t)(xs_ + quad * 4 + r) * SS + ys_ + cc] = acc1[r];
                    *(f4v*)(&O[(size_t)(ys_ + cc) * SS + xs_ + quad * 4]) = acc1;
                }
            }
        }
    } else {
        // -------- co-parent paths (block = (b, x)) --------
        const unsigned short* Zsrc = (t == 4) ? SHb : STb;
        int x  = bz - b * SS;
        int xt = x >> 4;
        float* Od = out + (size_t)t * OUTN + (size_t)bz * SS * SS;          // [y][z]
        float* Om = out + (size_t)t * OUTN + (size_t)b * SS * SS * SS;      // mirror base

        // z-tile ownership: waves 0-3 -> {w, w+8}; waves 4-7 -> {w}
        int zt0 = wave;
        int zt1 = wave + 8;
        bool two = (wave < 4);

        bf8v tb0[4], tb1[4];
        phase1(Zsrc + (size_t)(b * SS + zt0 * 16 + m) * DD + quad * 8, tb0);
        if (two) phase1(Zsrc + (size_t)(b * SS + zt1 * 16 + m) * DD + quad * 8, tb1);

        const unsigned short* Pbase = Pb + (size_t)b * SS * DD;
        int yt0 = (t == 4) ? 0 : xt;
        int zc0 = zt0 * 16 + m, zc1 = zt1 * 16 + m;

        for (int yt = yt0; yt < 12; ++yt) {
            const unsigned short* pr = Pbase + (size_t)(yt * 16 + m) * DD + quad * 8;
            bf8v pv0 = *(const bf8v*)(pr);
            bf8v pv1 = *(const bf8v*)(pr + 32);
            bf8v pv2 = *(const bf8v*)(pr + 64);
            bf8v pv3 = *(const bf8v*)(pr + 96);
            f4v acc0 = {0.f,0.f,0.f,0.f}, acc1 = {0.f,0.f,0.f,0.f};
            acc0 = mfma16(pv0, tb0[0], acc0);
            acc0 = mfma16(pv1, tb0[1], acc0);
            acc0 = mfma16(pv2, tb0[2], acc0);
            acc0 = mfma16(pv3, tb0[3], acc0);
            if (two) {
                acc1 = mfma16(pv0, tb1[0], acc1);
                acc1 = mfma16(pv1, tb1[1], acc1);
                acc1 = mfma16(pv2, tb1[2], acc1);
                acc1 = mfma16(pv3, tb1[3], acc1);
            }
            if (t == 4) {
                #pragma unroll
                for (int r = 0; r < 4; ++r)
                    Od[(size_t)(yt * 16 + quad * 4 + r) * SS + zc0] = acc0[r];
                if (two) {
                    #pragma unroll
                    for (int r = 0; r < 4; ++r)
                        Od[(size_t)(yt * 16 + quad * 4 + r) * SS + zc1] = acc1[r];
                }
            } else if (yt == xt) {
                #pragma unroll
                for (int r = 0; r < 4; ++r) {
                    int y = yt * 16 + quad * 4 + r;
                    if (y >= x) Od[(size_t)y * SS + zc0] = acc0[r];
                    if (y > x)  Om[(size_t)y * SS * SS + (size_t)x * SS + zc0] = acc0[r];
                }
                if (two) {
                    #pragma unroll
                    for (int r = 0; r < 4; ++r) {
                        int y = yt * 16 + quad * 4 + r;
                        if (y >= x) Od[(size_t)y * SS + zc1] = acc1[r];
                        if (y > x)  Om[(size_t)y * SS * SS + (size_t)x * SS + zc1] = acc1[r];
                    }
                }
            } else {
                #pragma unroll
                for (int r = 0; r < 4; ++r) {
                    int y = yt * 16 + quad * 4 + r;
                    Od[(size_t)y * SS + zc0] = acc0[r];
                    Om[(size_t)y * SS * SS + (size_t)x * SS + zc0] = acc0[r];
                }
                if (two) {
                    #pragma unroll
                    for (int r = 0; r < 4; ++r) {
                        int y = yt * 16 + quad * 4 + r;
                        Od[(size_t)y * SS + zc1] = acc1[r];
                        Om[(size_t)y * SS * SS + (size_t)x * SS + zc1] = acc1[r];
                    }
                }
            }
        }
    }
}

extern "C" void kernel_launch(void* const* d_in, const int* in_sizes, int n_in,
                              void* d_out, int out_size, void* d_ws, size_t ws_size,
                              hipStream_t stream)
{
    const float* x   = (const float*)d_in[0];
    const float* Wp  = (const float*)d_in[1];
    const float* bp  = (const float*)d_in[2];
    const float* Wh  = (const float*)d_in[3];
    const float* bh  = (const float*)d_in[4];
    const float* Wt  = (const float*)d_in[5];
    const float* bt  = (const float*)d_in[6];
    const float* W_span_ph = (const float*)d_in[7];
    const float* W_span_pt = (const float*)d_in[8];
    const float* W_ph_sib  = (const float*)d_in[9];
    const float* W_pt_sib  = (const float*)d_in[10];
    const float* W_ph_cop  = (const float*)d_in[11];
    const float* W_pt_cop  = (const float*)d_in[12];

    char* ws = (char*)d_ws;
    unsigned short* Pb    = (unsigned short*)ws;                 // 98304 B
    unsigned short* SHb   = Pb + 384 * 128;
    unsigned short* STb   = SHb + 384 * 128;
    unsigned short* Wprep = (unsigned short*)(ws + 294912);      // 6 x 4 MiB bf16
    unsigned short* SA    = (unsigned short*)(ws + 294912 + (size_t)6 * 2097152 * 2);
    float* part = (float*)SA;   // proj partials (2.36 MB) overlay SA region;
                                // consumed by proj_fin before stageA writes SA

    float* out  = (float*)d_out;

    proj_part<<<dim3(48, 3, 4), 256, 0, stream>>>(x, Wp, Wh, Wt, part);
    proj_fin<<<dim3(48, 3), 256, 0, stream>>>(part, bp, bh, bt, Pb, SHb, STb);
    prep_all<<<dim3(16, 128, 6), 256, 0, stream>>>(W_span_ph, W_span_pt, W_ph_sib,
                                                   W_pt_sib, W_ph_cop, W_pt_cop, Wprep);
    stageA<<<dim3(256, 6), 256, 0, stream>>>(Pb, Wprep, SA);
    stageB_all<<<dim3(384, 6), 512, 0, stream>>>(Pb, SHb, STb, SA, out);
}